// Round 5
// baseline (138.849 us; speedup 1.0000x reference)
//
#include <hip/hip_runtime.h>
#include <math.h>

#define MM    2048
#define CC    64
#define RH    4
#define NIF   461
#define INS   512
#define EPSN  1e-6f

typedef unsigned long long u64;

// ---- workspace layout (float offsets) ----
#define OFF_P     ((size_t)0)          // 256 x 512 params
#define OFF_U2    ((size_t)131072)     // 256 x 2048
#define OFF_MRW   ((size_t)655360)     // 256 x 2048
#define OFF_ALLOC ((size_t)1179648)    // 256 x 2048
#define OFF_SCAL  ((size_t)1703936)    // 256 x 2048 x 16 per-row scalars
#define OFF_W8    ((size_t)10092544)   // 256 x 2048 x 8  {alpha0..3, gamma0..3}
#define OFF_CR    ((size_t)14286848)   // 256 x 4
#define OFF_PART  ((size_t)14287872)   // 256 x 8 x 8 x 64 pass-2 partials
// params per batch: [0..255] folded read keys, [256..319] folded write key,
// [320..383] erase, [384..447] write vec, [448..450] alloc gate, [451] write gate

// ================= K1: interface + gates + u2 + mean-read =================
__global__ __launch_bounds__(512) void k1_interface(
    const float* __restrict__ xi, const float* __restrict__ W,
    const float* __restrict__ gamma, const float* __restrict__ beta,
    const float* __restrict__ read_w, const float* __restrict__ write_w,
    const float* __restrict__ usage, float* __restrict__ ws)
{
  const int b = blockIdx.x, tid = threadIdx.x;
  const int lane = tid & 63, wid = tid >> 6;
  __shared__ __align__(16) float s_xi[512], s_itf[512], s_act[512];
  __shared__ float sRed[24];

  s_xi[tid] = xi[(size_t)b*INS + tid];
  __syncthreads();

  {
    const float4 x0 = ((const float4*)s_xi)[lane*2];
    const float4 x1 = ((const float4*)s_xi)[lane*2+1];
    for (int col = wid; col < NIF; col += 8) {
      const float4* Wr = (const float4*)(W + (size_t)col*INS);
      float4 a0 = Wr[lane*2], a1 = Wr[lane*2+1];
      float p = a0.x*x0.x + a0.y*x0.y + a0.z*x0.z + a0.w*x0.w
              + a1.x*x1.x + a1.y*x1.y + a1.z*x1.z + a1.w*x1.w;
      #pragma unroll
      for (int off=1; off<64; off<<=1) p += __shfl_xor(p, off);
      if (lane==0) s_itf[col] = p;
    }
  }
  __syncthreads();

  {
    float v = (tid < NIF) ? s_itf[tid] : 0.f;
    float s = v, q = v*v;
    #pragma unroll
    for (int off=1; off<64; off<<=1) { s += __shfl_xor(s,off); q += __shfl_xor(q,off); }
    if (lane==0){ sRed[wid] = s; sRed[8+wid] = q; }
    __syncthreads();
    if (tid==0){
      float ts=0.f, tq=0.f;
      for (int i=0;i<8;i++){ ts+=sRed[i]; tq+=sRed[8+i]; }
      float mean = ts/(float)NIF;
      float var  = tq/(float)NIF - mean*mean;
      sRed[16]=mean; sRed[17]=rsqrtf(var+1e-5f);
    }
    __syncthreads();
    float mean = sRed[16], rstd = sRed[17];
    if (tid < NIF) {
      float g = (s_itf[tid]-mean)*rstd*gamma[tid] + beta[tid];
      float a;
      if      (tid < 256) a = tanhf(g);
      else if (tid < 260) a = fmaxf(g,0.f) + log1pf(expf(-fabsf(g)));
      else if (tid < 324) a = tanhf(g);
      else if (tid ==324) a = fmaxf(g,0.f) + log1pf(expf(-fabsf(g)));
      else if (tid < 389) a = 1.f/(1.f+expf(-g));
      else if (tid < 453) a = tanhf(g);
      else if (tid < 457) a = 1.f/(1.f+expf(-g));
      else if (tid < 460) a = g;
      else                a = 1.f/(1.f+expf(-g));
      s_act[tid] = a;
    }
  }
  __syncthreads();

  float* P = ws + OFF_P + (size_t)b*512;
  if (wid < 4) {
    float t = s_act[wid*64 + lane];
    float q = t*t;
    #pragma unroll
    for (int off=1; off<64; off<<=1) q += __shfl_xor(q,off);
    P[wid*64+lane] = t * (s_act[256+wid] / (sqrtf(q) + EPSN));
  } else if (wid == 4) {
    float t = s_act[260+lane];
    float q = t*t;
    #pragma unroll
    for (int off=1; off<64; off<<=1) q += __shfl_xor(q,off);
    P[256+lane] = t * (s_act[324] / (sqrtf(q) + EPSN));
  } else if (wid == 5) {
    P[320+lane] = s_act[325+lane];
    P[384+lane] = s_act[389+lane];
  } else if (wid == 6 && lane == 0) {
    float a0=s_act[457], a1=s_act[458], a2=s_act[459];
    float mx = fmaxf(a0, fmaxf(a1,a2));
    float e0=expf(a0-mx), e1=expf(a1-mx), e2=expf(a2-mx);
    float is = 1.f/(e0+e1+e2);
    P[448]=e0*is; P[449]=e1*is; P[450]=e2*is; P[451]=s_act[460];
  }

  {
    const float4* us4 = (const float4*)(usage   + (size_t)b*MM);
    const float4* wr4 = (const float4*)(write_w + (size_t)b*MM);
    const float4* rw4 = (const float4*)(read_w  + (size_t)b*RH*MM);
    const float fg0=s_act[453], fg1=s_act[454], fg2=s_act[455], fg3=s_act[456];
    float4 u = us4[tid], w = wr4[tid];
    float4 r0 = rw4[tid], r1 = rw4[512+tid], r2 = rw4[1024+tid], r3 = rw4[1536+tid];
    float4 mr, u2o;
    mr.x = 0.25f*(r0.x+r1.x+r2.x+r3.x);
    mr.y = 0.25f*(r0.y+r1.y+r2.y+r3.y);
    mr.z = 0.25f*(r0.z+r1.z+r2.z+r3.z);
    mr.w = 0.25f*(r0.w+r1.w+r2.w+r3.w);
    #define U2C(comp)                                                           \
    { float uu  = u.comp + (1.f-u.comp)*w.comp;                                 \
      float psi = (1.f-fg0*r0.comp)*(1.f-fg1*r1.comp)*(1.f-fg2*r2.comp)*(1.f-fg3*r3.comp); \
      u2o.comp = 1e-6f + (1.f-1e-6f)*(uu*psi); }
    U2C(x) U2C(y) U2C(z) U2C(w)
    #undef U2C
    ((float4*)(ws + OFF_MRW + (size_t)b*MM))[tid] = mr;
    ((float4*)(ws + OFF_U2  + (size_t)b*MM))[tid] = u2o;
  }
}

// ====== K2: hetero — blocks [0,256): sort+alloc; [256,2304): per-row scalars ======
__global__ __launch_bounds__(256) void k2_fused(
    const float* __restrict__ memory, float* __restrict__ ws)
{
  __shared__ __align__(16) u64 sKeys[2048];
  __shared__ float sT[260];
  const int tid = threadIdx.x;

  if (blockIdx.x < 256) {
    // ---------------- sort + allocation path ----------------
    const int b = blockIdx.x;
    const int lane = tid & 63, w = tid >> 6;
    const float* u2p = ws + OFF_U2 + (size_t)b*MM;
    for (int i = tid; i < MM; i += 256)
      sKeys[i] = ((u64)__float_as_uint(u2p[i])<<32) | (unsigned)i;
    __syncthreads();

    for (int k = 2; k <= MM; k <<= 1) {
      for (int j = k >> 1; j > 0; j >>= 1) {
        #pragma unroll 4
        for (int c = tid; c < MM/2; c += 256) {
          int i   = ((c & ~(j-1)) << 1) | (c & (j-1));
          int ixj = i | j;
          u64 a = sKeys[i], d = sKeys[ixj];
          bool up = ((i & k) == 0);
          if ((a > d) == up) { sKeys[i] = d; sKeys[ixj] = a; }
        }
        __syncthreads();
      }
    }

    float p[8];
    {
      float run = 1.f;
      #pragma unroll
      for (int e = 0; e < 8; ++e) {
        float su = __uint_as_float((unsigned)(sKeys[tid*8+e]>>32));
        run *= su; p[e] = run;
      }
      sT[tid] = run;
    }
    __syncthreads();
    float v = sT[tid];
    float incl = v;
    #pragma unroll
    for (int off=1; off<64; off<<=1) {
      float n = __shfl_up(incl, off);
      if (lane >= off) incl *= n;
    }
    float excl = __shfl_up(incl, 1);
    if (lane == 0) excl = 1.f;
    if (lane == 63) sT[256 + w] = incl;
    __syncthreads();
    float base = 1.f;
    for (int ww2 = 0; ww2 < w; ++ww2) base *= sT[256 + ww2];
    float E = base * excl;

    float* allocp = ws + OFF_ALLOC + (size_t)b*MM;
    #pragma unroll
    for (int e = 0; e < 8; ++e) {
      u64 kk = sKeys[tid*8+e];
      float su = __uint_as_float((unsigned)(kk>>32));
      unsigned idx = (unsigned)(kk & 0xFFFFFFFFu);
      float cp = E * (e ? p[e-1] : 1.f);
      allocp[idx] = (1.f - su) * cp;
    }
  } else {
    // ---------------- per-row scalar path: 14 scalars per memory row ----------------
    const int f = blockIdx.x - 256;
    const int b = f >> 3, slice = f & 7;
    const int q = tid & 7, rowg = tid >> 3;     // 8 lanes/row, 32 rows/iter
    const float* P = ws + OFF_P + (size_t)b*512;
    // per-lane constants: 8 columns [q*8, q*8+8)   (float4 index = float_off/4)
    const float4 wkA = ((const float4*)(P+256))[q*2], wkB = ((const float4*)(P+256))[q*2+1];
    const float4 eA  = ((const float4*)(P+320))[q*2], eB  = ((const float4*)(P+320))[q*2+1];
    const float4 wvA = ((const float4*)(P+384))[q*2], wvB = ((const float4*)(P+384))[q*2+1];
    const float4 k0A = ((const float4*)P)[      q*2], k0B = ((const float4*)P)[      q*2+1];
    const float4 k1A = ((const float4*)P)[ 16 + q*2], k1B = ((const float4*)P)[ 16 + q*2+1];
    const float4 k2A = ((const float4*)P)[ 32 + q*2], k2B = ((const float4*)P)[ 32 + q*2+1];
    const float4 k3A = ((const float4*)P)[ 48 + q*2], k3B = ((const float4*)P)[ 48 + q*2+1];
    const float4* mem4 = (const float4*)(memory + (size_t)b*MM*CC) + (size_t)slice*256*16;
    float4* sc4 = (float4*)(ws + OFF_SCAL) + ((size_t)b*MM + slice*256)*4;

    for (int it = 0; it < 8; ++it) {
      int m = it*32 + rowg;
      float4 vA = mem4[m*16 + q*2], vB = mem4[m*16 + q*2+1];
      float4 veA, veB;
      veA.x=vA.x*eA.x; veA.y=vA.y*eA.y; veA.z=vA.z*eA.z; veA.w=vA.w*eA.w;
      veB.x=vB.x*eB.x; veB.y=vB.y*eB.y; veB.z=vB.z*eB.z; veB.w=vB.w*eB.w;
      #define DOT(a,b) (a.x*b.x + a.y*b.y + a.z*b.z + a.w*b.w)
      float S  = DOT(vA,wkA) + DOT(vB,wkB);
      float A  = DOT(vA,vA)  + DOT(vB,vB);
      float B  = DOT(veA,vA) + DOT(veB,vB);
      float C  = DOT(veA,veA)+ DOT(veB,veB);
      float D  = DOT(vA,wvA) + DOT(vB,wvB);
      float E  = DOT(veA,wvA)+ DOT(veB,wvB);
      float G0 = DOT(vA,k0A) + DOT(vB,k0B);
      float G1 = DOT(vA,k1A) + DOT(vB,k1B);
      float G2 = DOT(vA,k2A) + DOT(vB,k2B);
      float G3 = DOT(vA,k3A) + DOT(vB,k3B);
      float H0 = DOT(veA,k0A)+ DOT(veB,k0B);
      float H1 = DOT(veA,k1A)+ DOT(veB,k1B);
      float H2 = DOT(veA,k2A)+ DOT(veB,k2B);
      float H3 = DOT(veA,k3A)+ DOT(veB,k3B);
      #undef DOT
      #pragma unroll
      for (int off=1; off<8; off<<=1) {
        S += __shfl_xor(S,off);   A += __shfl_xor(A,off);
        B += __shfl_xor(B,off);   C += __shfl_xor(C,off);
        D += __shfl_xor(D,off);   E += __shfl_xor(E,off);
        G0 += __shfl_xor(G0,off); G1 += __shfl_xor(G1,off);
        G2 += __shfl_xor(G2,off); G3 += __shfl_xor(G3,off);
        H0 += __shfl_xor(H0,off); H1 += __shfl_xor(H1,off);
        H2 += __shfl_xor(H2,off); H3 += __shfl_xor(H3,off);
      }
      if (q == 0) {
        float4 o0; o0.x=S;  o0.y=A;  o0.z=B;  o0.w=C;
        float4 o1; o1.x=D;  o1.y=E;  o1.z=0;  o1.w=0;
        float4 o2; o2.x=G0; o2.y=G1; o2.z=G2; o2.w=G3;
        float4 o3; o3.x=H0; o3.y=H1; o3.z=H2; o3.w=H3;
        sc4[m*4+0]=o0; sc4[m*4+1]=o1; sc4[m*4+2]=o2; sc4[m*4+3]=o3;
      }
    }
  }
}

// ===== K3: per-batch — softmaxes (exact) + ww + read weights alpha/gamma =====
__global__ __launch_bounds__(256) void k3_weights(float* __restrict__ ws)
{
  const int b = blockIdx.x, tid = threadIdx.x;
  const int lane = tid & 63, w = tid >> 6;   // 4 waves
  __shared__ float sWraw[2048];
  __shared__ float sWw[2048];
  __shared__ float sSc[4*2048];
  __shared__ float sR[64];
  __shared__ float sKF[8];

  const float* P = ws + OFF_P + (size_t)b*512;
  const float* scal = ws + OFF_SCAL + (size_t)b*MM*16;
  const float4* sc4 = (const float4*)scal;

  // K_r = wv.k_r, F = |wv|^2
  if (tid < 64) {
    float wv = P[384+tid];
    float p0=wv*P[tid], p1=wv*P[64+tid], p2=wv*P[128+tid], p3=wv*P[192+tid], f=wv*wv;
    #pragma unroll
    for (int off=1; off<64; off<<=1) {
      p0+=__shfl_xor(p0,off); p1+=__shfl_xor(p1,off); p2+=__shfl_xor(p2,off);
      p3+=__shfl_xor(p3,off); f+=__shfl_xor(f,off);
    }
    if (tid==0){ sKF[0]=p0; sKF[1]=p1; sKF[2]=p2; sKF[3]=p3; sKF[4]=f; }
  }
  __syncthreads();

  // pass 1: raw write scores + max
  float lm = -INFINITY;
  #pragma unroll
  for (int k = 0; k < 8; ++k) {
    int m = tid + k*256;
    float4 s0 = sc4[m*4];
    float wraw = s0.x / (sqrtf(s0.y)+EPSN);
    sWraw[m] = wraw;
    lm = fmaxf(lm, wraw);
  }
  #pragma unroll
  for (int off=1; off<64; off<<=1) lm = fmaxf(lm, __shfl_xor(lm,off));
  if (lane==0) sR[w] = lm;
  __syncthreads();
  const float Mw = fmaxf(fmaxf(sR[0],sR[1]), fmaxf(sR[2],sR[3]));
  // pass 2: sum exp
  float ls = 0.f;
  #pragma unroll
  for (int k = 0; k < 8; ++k) ls += expf(sWraw[tid + k*256] - Mw);
  #pragma unroll
  for (int off=1; off<64; off<<=1) ls += __shfl_xor(ls,off);
  if (lane==0) sR[4+w] = ls;
  __syncthreads();
  const float invW = 1.f/(sR[4]+sR[5]+sR[6]+sR[7]);

  const float ag0=P[448], ag1=P[449], ag2=P[450], wg=P[451];
  const float K0=sKF[0], K1=sKF[1], K2=sKF[2], K3=sKF[3], F=sKF[4];
  const float* mrwp = ws + OFF_MRW   + (size_t)b*MM;
  const float* alp  = ws + OFF_ALLOC + (size_t)b*MM;

  // pass 3: ww + read scores + head maxes
  float hm0=-INFINITY, hm1=-INFINITY, hm2=-INFINITY, hm3=-INFINITY;
  #pragma unroll
  for (int k = 0; k < 8; ++k) {
    int m = tid + k*256;
    float wcw = expf(sWraw[m]-Mw)*invW;
    float wwv = wg*(ag0*mrwp[m] + ag1*alp[m] + ag2*wcw);
    sWw[m] = wwv;
    float4 s0 = sc4[m*4], s1 = sc4[m*4+1], sG = sc4[m*4+2], sH = sc4[m*4+3];
    float nsq = s0.y + 2.f*wwv*(s1.x - s0.z) + wwv*wwv*(s0.w - 2.f*s1.y + F);
    float rstd = 1.f/(sqrtf(fmaxf(nsq,0.f))+EPSN);
    float c0 = (sG.x + wwv*(K0 - sH.x))*rstd;
    float c1 = (sG.y + wwv*(K1 - sH.y))*rstd;
    float c2 = (sG.z + wwv*(K2 - sH.z))*rstd;
    float c3 = (sG.w + wwv*(K3 - sH.w))*rstd;
    sSc[       m] = c0; sSc[2048 + m] = c1;
    sSc[4096 + m] = c2; sSc[6144 + m] = c3;
    hm0=fmaxf(hm0,c0); hm1=fmaxf(hm1,c1); hm2=fmaxf(hm2,c2); hm3=fmaxf(hm3,c3);
  }
  #pragma unroll
  for (int off=1; off<64; off<<=1) {
    hm0=fmaxf(hm0,__shfl_xor(hm0,off)); hm1=fmaxf(hm1,__shfl_xor(hm1,off));
    hm2=fmaxf(hm2,__shfl_xor(hm2,off)); hm3=fmaxf(hm3,__shfl_xor(hm3,off));
  }
  if (lane==0){ sR[8+w*4]=hm0; sR[9+w*4]=hm1; sR[10+w*4]=hm2; sR[11+w*4]=hm3; }
  __syncthreads();
  const float M0 = fmaxf(fmaxf(sR[8], sR[12]), fmaxf(sR[16], sR[20]));
  const float M1 = fmaxf(fmaxf(sR[9], sR[13]), fmaxf(sR[17], sR[21]));
  const float M2 = fmaxf(fmaxf(sR[10],sR[14]), fmaxf(sR[18], sR[22]));
  const float M3 = fmaxf(fmaxf(sR[11],sR[15]), fmaxf(sR[19], sR[23]));
  // pass 4: per-head sums
  float h0=0.f,h1=0.f,h2=0.f,h3=0.f;
  #pragma unroll
  for (int k = 0; k < 8; ++k) {
    int m = tid + k*256;
    h0 += expf(sSc[       m]-M0); h1 += expf(sSc[2048 + m]-M1);
    h2 += expf(sSc[4096 + m]-M2); h3 += expf(sSc[6144 + m]-M3);
  }
  #pragma unroll
  for (int off=1; off<64; off<<=1) {
    h0+=__shfl_xor(h0,off); h1+=__shfl_xor(h1,off);
    h2+=__shfl_xor(h2,off); h3+=__shfl_xor(h3,off);
  }
  if (lane==0){ sR[24+w*4]=h0; sR[25+w*4]=h1; sR[26+w*4]=h2; sR[27+w*4]=h3; }
  __syncthreads();
  const float i0 = 1.f/(sR[24]+sR[28]+sR[32]+sR[36]);
  const float i1 = 1.f/(sR[25]+sR[29]+sR[33]+sR[37]);
  const float i2 = 1.f/(sR[26]+sR[30]+sR[34]+sR[38]);
  const float i3 = 1.f/(sR[27]+sR[31]+sR[35]+sR[39]);
  // pass 5: write alpha/gamma, accumulate cr
  float4* w84 = (float4*)(ws + OFF_W8 + (size_t)b*MM*8);
  float cr0=0.f, cr1=0.f, cr2=0.f, cr3=0.f;
  #pragma unroll
  for (int k = 0; k < 8; ++k) {
    int m = tid + k*256;
    float wwv = sWw[m];
    float a0 = expf(sSc[       m]-M0)*i0;
    float a1 = expf(sSc[2048 + m]-M1)*i1;
    float a2 = expf(sSc[4096 + m]-M2)*i2;
    float a3 = expf(sSc[6144 + m]-M3)*i3;
    float4 oa; oa.x=a0; oa.y=a1; oa.z=a2; oa.w=a3;
    float4 og; og.x=a0*wwv; og.y=a1*wwv; og.z=a2*wwv; og.w=a3*wwv;
    w84[m*2] = oa; w84[m*2+1] = og;
    cr0 += og.x; cr1 += og.y; cr2 += og.z; cr3 += og.w;
  }
  #pragma unroll
  for (int off=1; off<64; off<<=1) {
    cr0+=__shfl_xor(cr0,off); cr1+=__shfl_xor(cr1,off);
    cr2+=__shfl_xor(cr2,off); cr3+=__shfl_xor(cr3,off);
  }
  if (lane==0){ sR[40+w*4]=cr0; sR[41+w*4]=cr1; sR[42+w*4]=cr2; sR[43+w*4]=cr3; }
  __syncthreads();
  if (tid < 4)
    ws[OFF_CR + (size_t)b*4 + tid] =
      sR[40+tid] + sR[44+tid] + sR[48+tid] + sR[52+tid];
}

// ========== K4: dual-weighted row reduction over memory (L3 pass) =========
__global__ __launch_bounds__(256) void k4_reduce(
    const float* __restrict__ memory, const float* __restrict__ ws,
    float* __restrict__ wso)
{
  const int slice = blockIdx.x, b = blockIdx.y;
  const int tid = threadIdx.x;
  const int w = tid >> 6, lane = tid & 63;
  const int rq = lane >> 4, cq = lane & 15;   // 4 rows x 16 colquads per wave
  __shared__ __align__(16) float ldsW8[256*8];
  __shared__ __align__(16) float ldsP[4*16*32];

  // stage weights (256 rows x 8)
  {
    const float4* g = (const float4*)(ws + OFF_W8 + ((size_t)b*MM + slice*256)*8);
    ((float4*)ldsW8)[tid] = g[tid];
    ((float4*)ldsW8)[tid+256] = g[tid+256];
  }
  __syncthreads();

  const float4* mem4 = (const float4*)(memory + (size_t)b*MM*CC) + (size_t)slice*256*16;
  float4 acc[8];
  #pragma unroll
  for (int j=0;j<8;++j){ acc[j].x=0;acc[j].y=0;acc[j].z=0;acc[j].w=0; }

  #pragma unroll 4
  for (int i = 0; i < 16; ++i) {
    int m = w*64 + i*4 + rq;
    float4 v = mem4[m*16 + cq];
    float4 wa = *(const float4*)&ldsW8[m*8];
    float4 wb = *(const float4*)&ldsW8[m*8+4];
    #define ACC(j, s) { acc[j].x += (s)*v.x; acc[j].y += (s)*v.y; acc[j].z += (s)*v.z; acc[j].w += (s)*v.w; }
    ACC(0, wa.x) ACC(1, wa.y) ACC(2, wa.z) ACC(3, wa.w)
    ACC(4, wb.x) ACC(5, wb.y) ACC(6, wb.z) ACC(7, wb.w)
    #undef ACC
  }
  // reduce across the 4 row-quadrants within the wave
  #pragma unroll
  for (int j=0;j<8;++j){
    #pragma unroll
    for (int off=16; off<64; off<<=1) {
      acc[j].x += __shfl_xor(acc[j].x, off);
      acc[j].y += __shfl_xor(acc[j].y, off);
      acc[j].z += __shfl_xor(acc[j].z, off);
      acc[j].w += __shfl_xor(acc[j].w, off);
    }
  }
  if (rq == 0) {
    float4* p4 = (float4*)&ldsP[(w*16 + cq)*32];
    #pragma unroll
    for (int j=0;j<8;++j) p4[j] = acc[j];
  }
  __syncthreads();
  // combine 4 waves -> write partials [b][slice][j][c]
  {
    int jj = tid >> 6;          // 0..3
    int c  = tid & 63;
    int cq2 = c >> 2, ci = c & 3;
    float s1 = 0.f, s2 = 0.f;
    #pragma unroll
    for (int g=0; g<4; ++g) {
      s1 += ldsP[(g*16 + cq2)*32 +  jj*4    + ci];
      s2 += ldsP[(g*16 + cq2)*32 + (jj+4)*4 + ci];
    }
    float* part = wso + OFF_PART + (((size_t)b*8 + slice)*8)*64;
    part[ jj   *64 + c] = s1;
    part[(jj+4)*64 + c] = s2;
  }
}

// ================= K5: combine slices, apply erase/write terms ============
__global__ __launch_bounds__(256) void k5_combine(
    const float* __restrict__ ws, float* __restrict__ out)
{
  const int b = blockIdx.x, tid = threadIdx.x;
  const int h = tid >> 6, c = tid & 63;
  const float* P = ws + OFF_P + (size_t)b*512;
  float S1 = 0.f, S2 = 0.f;
  #pragma unroll
  for (int s = 0; s < 8; ++s) {
    const float* part = ws + OFF_PART + (((size_t)b*8 + s)*8)*64;
    S1 += part[ h   *64 + c];
    S2 += part[(h+4)*64 + c];
  }
  float e  = P[320+c];
  float wv = P[384+c];
  float cr = ws[OFF_CR + (size_t)b*4 + h];
  out[((size_t)b<<8) + h*64 + c] = S1 - e*S2 + cr*wv;
}

extern "C" void kernel_launch(void* const* d_in, const int* in_sizes, int n_in,
                              void* d_out, int out_size, void* d_ws, size_t ws_size,
                              hipStream_t stream) {
  const float* xi      = (const float*)d_in[0];
  const float* W       = (const float*)d_in[1];
  const float* gamma   = (const float*)d_in[2];
  const float* beta    = (const float*)d_in[3];
  const float* memory  = (const float*)d_in[4];
  const float* read_w  = (const float*)d_in[5];
  const float* write_w = (const float*)d_in[6];
  const float* usage   = (const float*)d_in[7];
  float* ws  = (float*)d_ws;
  float* out = (float*)d_out;

  k1_interface<<<dim3(256), dim3(512), 0, stream>>>(xi, W, gamma, beta, read_w, write_w, usage, ws);
  k2_fused   <<<dim3(2304), dim3(256), 0, stream>>>(memory, ws);
  k3_weights <<<dim3(256), dim3(256), 0, stream>>>(ws);
  k4_reduce  <<<dim3(8,256), dim3(256), 0, stream>>>(memory, ws, ws);
  k5_combine <<<dim3(256), dim3(256), 0, stream>>>(ws, out);
}

// Round 6
// 136.870 us; speedup vs baseline: 1.0145x; 1.0145x over previous
//
#include <hip/hip_runtime.h>
#include <math.h>

#define MM    2048
#define CC    64
#define RH    4
#define NIF   461
#define INS   512
#define EPSN  1e-6f

typedef unsigned long long u64;

// ---- workspace layout (float offsets) ----
#define OFF_P     ((size_t)0)          // 256 x 512 params
#define OFF_U2    ((size_t)131072)     // 256 x 2048
#define OFF_MRW   ((size_t)655360)     // 256 x 2048
#define OFF_ALLOC ((size_t)1179648)    // 256 x 2048
#define OFF_SCAL  ((size_t)1703936)    // 256 x 2048 x 16 per-row scalars
#define OFF_W8    ((size_t)10092544)   // 256 x 2048 x 8  {alpha0..3, gamma0..3}
#define OFF_CR    ((size_t)14286848)   // 256 x 4
#define OFF_PART  ((size_t)14287872)   // 256 x 8 x 8 x 64 pass-2 partials
// params per batch: [0..255] folded read keys, [256..319] folded write key,
// [320..383] erase, [384..447] write vec, [448..450] alloc gate, [451] write gate

// ================= K1: interface + gates + u2 + mean-read =================
__global__ __launch_bounds__(512) void k1_interface(
    const float* __restrict__ xi, const float* __restrict__ W,
    const float* __restrict__ gamma, const float* __restrict__ beta,
    const float* __restrict__ read_w, const float* __restrict__ write_w,
    const float* __restrict__ usage, float* __restrict__ ws)
{
  const int b = blockIdx.x, tid = threadIdx.x;
  const int lane = tid & 63, wid = tid >> 6;
  __shared__ __align__(16) float s_xi[512], s_itf[512], s_act[512];
  __shared__ float sRed[24];

  s_xi[tid] = xi[(size_t)b*INS + tid];
  __syncthreads();

  {
    const float4 x0 = ((const float4*)s_xi)[lane*2];
    const float4 x1 = ((const float4*)s_xi)[lane*2+1];
    for (int col = wid; col < NIF; col += 8) {
      const float4* Wr = (const float4*)(W + (size_t)col*INS);
      float4 a0 = Wr[lane*2], a1 = Wr[lane*2+1];
      float p = a0.x*x0.x + a0.y*x0.y + a0.z*x0.z + a0.w*x0.w
              + a1.x*x1.x + a1.y*x1.y + a1.z*x1.z + a1.w*x1.w;
      #pragma unroll
      for (int off=1; off<64; off<<=1) p += __shfl_xor(p, off);
      if (lane==0) s_itf[col] = p;
    }
  }
  __syncthreads();

  {
    float v = (tid < NIF) ? s_itf[tid] : 0.f;
    float s = v, q = v*v;
    #pragma unroll
    for (int off=1; off<64; off<<=1) { s += __shfl_xor(s,off); q += __shfl_xor(q,off); }
    if (lane==0){ sRed[wid] = s; sRed[8+wid] = q; }
    __syncthreads();
    if (tid==0){
      float ts=0.f, tq=0.f;
      for (int i=0;i<8;i++){ ts+=sRed[i]; tq+=sRed[8+i]; }
      float mean = ts/(float)NIF;
      float var  = tq/(float)NIF - mean*mean;
      sRed[16]=mean; sRed[17]=rsqrtf(var+1e-5f);
    }
    __syncthreads();
    float mean = sRed[16], rstd = sRed[17];
    if (tid < NIF) {
      float g = (s_itf[tid]-mean)*rstd*gamma[tid] + beta[tid];
      float a;
      if      (tid < 256) a = tanhf(g);
      else if (tid < 260) a = fmaxf(g,0.f) + log1pf(expf(-fabsf(g)));
      else if (tid < 324) a = tanhf(g);
      else if (tid ==324) a = fmaxf(g,0.f) + log1pf(expf(-fabsf(g)));
      else if (tid < 389) a = 1.f/(1.f+expf(-g));
      else if (tid < 453) a = tanhf(g);
      else if (tid < 457) a = 1.f/(1.f+expf(-g));
      else if (tid < 460) a = g;
      else                a = 1.f/(1.f+expf(-g));
      s_act[tid] = a;
    }
  }
  __syncthreads();

  float* P = ws + OFF_P + (size_t)b*512;
  if (wid < 4) {
    float t = s_act[wid*64 + lane];
    float q = t*t;
    #pragma unroll
    for (int off=1; off<64; off<<=1) q += __shfl_xor(q,off);
    P[wid*64+lane] = t * (s_act[256+wid] / (sqrtf(q) + EPSN));
  } else if (wid == 4) {
    float t = s_act[260+lane];
    float q = t*t;
    #pragma unroll
    for (int off=1; off<64; off<<=1) q += __shfl_xor(q,off);
    P[256+lane] = t * (s_act[324] / (sqrtf(q) + EPSN));
  } else if (wid == 5) {
    P[320+lane] = s_act[325+lane];
    P[384+lane] = s_act[389+lane];
  } else if (wid == 6 && lane == 0) {
    float a0=s_act[457], a1=s_act[458], a2=s_act[459];
    float mx = fmaxf(a0, fmaxf(a1,a2));
    float e0=expf(a0-mx), e1=expf(a1-mx), e2=expf(a2-mx);
    float is = 1.f/(e0+e1+e2);
    P[448]=e0*is; P[449]=e1*is; P[450]=e2*is; P[451]=s_act[460];
  }

  {
    const float4* us4 = (const float4*)(usage   + (size_t)b*MM);
    const float4* wr4 = (const float4*)(write_w + (size_t)b*MM);
    const float4* rw4 = (const float4*)(read_w  + (size_t)b*RH*MM);
    const float fg0=s_act[453], fg1=s_act[454], fg2=s_act[455], fg3=s_act[456];
    float4 u = us4[tid], w = wr4[tid];
    float4 r0 = rw4[tid], r1 = rw4[512+tid], r2 = rw4[1024+tid], r3 = rw4[1536+tid];
    float4 mr, u2o;
    mr.x = 0.25f*(r0.x+r1.x+r2.x+r3.x);
    mr.y = 0.25f*(r0.y+r1.y+r2.y+r3.y);
    mr.z = 0.25f*(r0.z+r1.z+r2.z+r3.z);
    mr.w = 0.25f*(r0.w+r1.w+r2.w+r3.w);
    #define U2C(comp)                                                           \
    { float uu  = u.comp + (1.f-u.comp)*w.comp;                                 \
      float psi = (1.f-fg0*r0.comp)*(1.f-fg1*r1.comp)*(1.f-fg2*r2.comp)*(1.f-fg3*r3.comp); \
      u2o.comp = 1e-6f + (1.f-1e-6f)*(uu*psi); }
    U2C(x) U2C(y) U2C(z) U2C(w)
    #undef U2C
    ((float4*)(ws + OFF_MRW + (size_t)b*MM))[tid] = mr;
    ((float4*)(ws + OFF_U2  + (size_t)b*MM))[tid] = u2o;
  }
}

// ====== K2: hetero — blocks [0,256): sort+alloc; [256,2304): per-row scalars ======
__global__ __launch_bounds__(256) void k2_fused(
    const float* __restrict__ memory, float* __restrict__ ws)
{
  __shared__ __align__(16) u64 sKeys[2048];
  __shared__ float sT[260];
  const int tid = threadIdx.x;

  if (blockIdx.x < 256) {
    // ---------------- sort + allocation path ----------------
    const int b = blockIdx.x;
    const int lane = tid & 63, w = tid >> 6;
    const float* u2p = ws + OFF_U2 + (size_t)b*MM;
    for (int i = tid; i < MM; i += 256)
      sKeys[i] = ((u64)__float_as_uint(u2p[i])<<32) | (unsigned)i;
    __syncthreads();

    for (int k = 2; k <= MM; k <<= 1) {
      for (int j = k >> 1; j > 0; j >>= 1) {
        #pragma unroll 4
        for (int c = tid; c < MM/2; c += 256) {
          int i   = ((c & ~(j-1)) << 1) | (c & (j-1));
          int ixj = i | j;
          u64 a = sKeys[i], d = sKeys[ixj];
          bool up = ((i & k) == 0);
          if ((a > d) == up) { sKeys[i] = d; sKeys[ixj] = a; }
        }
        __syncthreads();
      }
    }

    float p[8];
    {
      float run = 1.f;
      #pragma unroll
      for (int e = 0; e < 8; ++e) {
        float su = __uint_as_float((unsigned)(sKeys[tid*8+e]>>32));
        run *= su; p[e] = run;
      }
      sT[tid] = run;
    }
    __syncthreads();
    float v = sT[tid];
    float incl = v;
    #pragma unroll
    for (int off=1; off<64; off<<=1) {
      float n = __shfl_up(incl, off);
      if (lane >= off) incl *= n;
    }
    float excl = __shfl_up(incl, 1);
    if (lane == 0) excl = 1.f;
    if (lane == 63) sT[256 + w] = incl;
    __syncthreads();
    float base = 1.f;
    for (int ww2 = 0; ww2 < w; ++ww2) base *= sT[256 + ww2];
    float E = base * excl;

    float* allocp = ws + OFF_ALLOC + (size_t)b*MM;
    #pragma unroll
    for (int e = 0; e < 8; ++e) {
      u64 kk = sKeys[tid*8+e];
      float su = __uint_as_float((unsigned)(kk>>32));
      unsigned idx = (unsigned)(kk & 0xFFFFFFFFu);
      float cp = E * (e ? p[e-1] : 1.f);
      allocp[idx] = (1.f - su) * cp;
    }
  } else {
    // ---------------- per-row scalar path: 14 scalars per memory row ----------------
    const int f = blockIdx.x - 256;
    const int b = f >> 3, slice = f & 7;
    const int q = tid & 7, rowg = tid >> 3;     // 8 lanes/row, 32 rows/iter
    const float* P = ws + OFF_P + (size_t)b*512;
    // per-lane constants: 8 columns [q*8, q*8+8)   (float4 index = float_off/4)
    const float4 wkA = ((const float4*)(P+256))[q*2], wkB = ((const float4*)(P+256))[q*2+1];
    const float4 eA  = ((const float4*)(P+320))[q*2], eB  = ((const float4*)(P+320))[q*2+1];
    const float4 wvA = ((const float4*)(P+384))[q*2], wvB = ((const float4*)(P+384))[q*2+1];
    const float4 k0A = ((const float4*)P)[      q*2], k0B = ((const float4*)P)[      q*2+1];
    const float4 k1A = ((const float4*)P)[ 16 + q*2], k1B = ((const float4*)P)[ 16 + q*2+1];
    const float4 k2A = ((const float4*)P)[ 32 + q*2], k2B = ((const float4*)P)[ 32 + q*2+1];
    const float4 k3A = ((const float4*)P)[ 48 + q*2], k3B = ((const float4*)P)[ 48 + q*2+1];
    const float4* mem4 = (const float4*)(memory + (size_t)b*MM*CC) + (size_t)slice*256*16;
    float4* sc4 = (float4*)(ws + OFF_SCAL) + ((size_t)b*MM + slice*256)*4;

    for (int it = 0; it < 8; ++it) {
      int m = it*32 + rowg;
      float4 vA = mem4[m*16 + q*2], vB = mem4[m*16 + q*2+1];
      float4 veA, veB;
      veA.x=vA.x*eA.x; veA.y=vA.y*eA.y; veA.z=vA.z*eA.z; veA.w=vA.w*eA.w;
      veB.x=vB.x*eB.x; veB.y=vB.y*eB.y; veB.z=vB.z*eB.z; veB.w=vB.w*eB.w;
      #define DOT(a,b) (a.x*b.x + a.y*b.y + a.z*b.z + a.w*b.w)
      float S  = DOT(vA,wkA) + DOT(vB,wkB);
      float A  = DOT(vA,vA)  + DOT(vB,vB);
      float B  = DOT(veA,vA) + DOT(veB,vB);
      float C  = DOT(veA,veA)+ DOT(veB,veB);
      float D  = DOT(vA,wvA) + DOT(vB,wvB);
      float E  = DOT(veA,wvA)+ DOT(veB,wvB);
      float G0 = DOT(vA,k0A) + DOT(vB,k0B);
      float G1 = DOT(vA,k1A) + DOT(vB,k1B);
      float G2 = DOT(vA,k2A) + DOT(vB,k2B);
      float G3 = DOT(vA,k3A) + DOT(vB,k3B);
      float H0 = DOT(veA,k0A)+ DOT(veB,k0B);
      float H1 = DOT(veA,k1A)+ DOT(veB,k1B);
      float H2 = DOT(veA,k2A)+ DOT(veB,k2B);
      float H3 = DOT(veA,k3A)+ DOT(veB,k3B);
      #undef DOT
      #pragma unroll
      for (int off=1; off<8; off<<=1) {
        S += __shfl_xor(S,off);   A += __shfl_xor(A,off);
        B += __shfl_xor(B,off);   C += __shfl_xor(C,off);
        D += __shfl_xor(D,off);   E += __shfl_xor(E,off);
        G0 += __shfl_xor(G0,off); G1 += __shfl_xor(G1,off);
        G2 += __shfl_xor(G2,off); G3 += __shfl_xor(G3,off);
        H0 += __shfl_xor(H0,off); H1 += __shfl_xor(H1,off);
        H2 += __shfl_xor(H2,off); H3 += __shfl_xor(H3,off);
      }
      if (q == 0) {
        float4 o0; o0.x=S;  o0.y=A;  o0.z=B;  o0.w=C;
        float4 o1; o1.x=D;  o1.y=E;  o1.z=0;  o1.w=0;
        float4 o2; o2.x=G0; o2.y=G1; o2.z=G2; o2.w=G3;
        float4 o3; o3.x=H0; o3.y=H1; o3.z=H2; o3.w=H3;
        sc4[m*4+0]=o0; sc4[m*4+1]=o1; sc4[m*4+2]=o2; sc4[m*4+3]=o3;
      }
    }
  }
}

// ===== K3: per-batch weights — 3 light passes, no-max softmax, 512 thr =====
__global__ __launch_bounds__(512) void k3_weights(float* __restrict__ ws)
{
  const int b = blockIdx.x, tid = threadIdx.x;
  const int lane = tid & 63, w = tid >> 6;   // 8 waves
  __shared__ float sEw[2048];
  __shared__ float sWw[2048];
  __shared__ float sE0[2048], sE1[2048], sE2[2048], sE3[2048];
  __shared__ float sR[64];
  __shared__ float sKF[8];

  const float* P = ws + OFF_P + (size_t)b*512;
  const float4* sc4 = (const float4*)(ws + OFF_SCAL + (size_t)b*MM*16);

  // K_r = wv.k_r, F = |wv|^2 (single wave)
  if (tid < 64) {
    float wv = P[384+tid];
    float p0=wv*P[tid], p1=wv*P[64+tid], p2=wv*P[128+tid], p3=wv*P[192+tid], f=wv*wv;
    #pragma unroll
    for (int off=1; off<64; off<<=1) {
      p0+=__shfl_xor(p0,off); p1+=__shfl_xor(p1,off); p2+=__shfl_xor(p2,off);
      p3+=__shfl_xor(p3,off); f+=__shfl_xor(f,off);
    }
    if (tid==0){ sKF[0]=p0; sKF[1]=p1; sKF[2]=p2; sKF[3]=p3; sKF[4]=f; }
  }

  // pass A: exp(write score) without max (scores bounded by strength, safe)
  float ls = 0.f;
  #pragma unroll
  for (int k = 0; k < 4; ++k) {
    int m = tid + k*512;
    float4 s0 = sc4[m*4];
    float ew = expf(s0.x / (sqrtf(s0.y)+EPSN));
    sEw[m] = ew;
    ls += ew;
  }
  #pragma unroll
  for (int off=1; off<64; off<<=1) ls += __shfl_xor(ls,off);
  if (lane==0) sR[w] = ls;
  __syncthreads();
  const float invW = 1.f/(sR[0]+sR[1]+sR[2]+sR[3]+sR[4]+sR[5]+sR[6]+sR[7]);

  const float ag0=P[448], ag1=P[449], ag2=P[450], wg=P[451];
  const float K0=sKF[0], K1=sKF[1], K2=sKF[2], K3=sKF[3], F=sKF[4];
  const float* mrwp = ws + OFF_MRW   + (size_t)b*MM;
  const float* alp  = ws + OFF_ALLOC + (size_t)b*MM;

  // pass B: ww + read scores (closed form) + per-head exp sums (no max)
  float h0=0.f,h1=0.f,h2=0.f,h3=0.f;
  #pragma unroll
  for (int k = 0; k < 4; ++k) {
    int m = tid + k*512;
    float wwv = wg*(ag0*mrwp[m] + ag1*alp[m] + ag2*sEw[m]*invW);
    sWw[m] = wwv;
    float4 s0 = sc4[m*4], s1 = sc4[m*4+1], sG = sc4[m*4+2], sH = sc4[m*4+3];
    float nsq = s0.y + 2.f*wwv*(s1.x - s0.z) + wwv*wwv*(s0.w - 2.f*s1.y + F);
    float rstd = 1.f/(sqrtf(fmaxf(nsq,0.f))+EPSN);
    float e0 = expf((sG.x + wwv*(K0 - sH.x))*rstd);
    float e1 = expf((sG.y + wwv*(K1 - sH.y))*rstd);
    float e2 = expf((sG.z + wwv*(K2 - sH.z))*rstd);
    float e3 = expf((sG.w + wwv*(K3 - sH.w))*rstd);
    sE0[m]=e0; sE1[m]=e1; sE2[m]=e2; sE3[m]=e3;
    h0+=e0; h1+=e1; h2+=e2; h3+=e3;
  }
  #pragma unroll
  for (int off=1; off<64; off<<=1) {
    h0+=__shfl_xor(h0,off); h1+=__shfl_xor(h1,off);
    h2+=__shfl_xor(h2,off); h3+=__shfl_xor(h3,off);
  }
  if (lane==0){ sR[8+w*4]=h0; sR[9+w*4]=h1; sR[10+w*4]=h2; sR[11+w*4]=h3; }
  __syncthreads();
  float t0=0.f,t1=0.f,t2=0.f,t3=0.f;
  #pragma unroll
  for (int g=0; g<8; ++g){ t0+=sR[8+g*4]; t1+=sR[9+g*4]; t2+=sR[10+g*4]; t3+=sR[11+g*4]; }
  const float i0=1.f/t0, i1=1.f/t1, i2=1.f/t2, i3=1.f/t3;

  // pass C: alpha/gamma out + cr accumulation
  float4* w84 = (float4*)(ws + OFF_W8 + (size_t)b*MM*8);
  float cr0=0.f, cr1=0.f, cr2=0.f, cr3=0.f;
  #pragma unroll
  for (int k = 0; k < 4; ++k) {
    int m = tid + k*512;
    float wwv = sWw[m];
    float a0 = sE0[m]*i0, a1 = sE1[m]*i1, a2 = sE2[m]*i2, a3 = sE3[m]*i3;
    float4 oa; oa.x=a0; oa.y=a1; oa.z=a2; oa.w=a3;
    float4 og; og.x=a0*wwv; og.y=a1*wwv; og.z=a2*wwv; og.w=a3*wwv;
    w84[m*2] = oa; w84[m*2+1] = og;
    cr0 += og.x; cr1 += og.y; cr2 += og.z; cr3 += og.w;
  }
  #pragma unroll
  for (int off=1; off<64; off<<=1) {
    cr0+=__shfl_xor(cr0,off); cr1+=__shfl_xor(cr1,off);
    cr2+=__shfl_xor(cr2,off); cr3+=__shfl_xor(cr3,off);
  }
  if (lane==0){ sR[32+w*4]=cr0; sR[33+w*4]=cr1; sR[34+w*4]=cr2; sR[35+w*4]=cr3; }
  __syncthreads();
  if (tid < 4) {
    float s = 0.f;
    #pragma unroll
    for (int g=0; g<8; ++g) s += sR[32+g*4+tid];
    ws[OFF_CR + (size_t)b*4 + tid] = s;
  }
}

// ========== K4: dual-weighted row reduction over memory (L3 pass) =========
__global__ __launch_bounds__(256) void k4_reduce(
    const float* __restrict__ memory, const float* __restrict__ ws,
    float* __restrict__ wso)
{
  const int slice = blockIdx.x, b = blockIdx.y;
  const int tid = threadIdx.x;
  const int w = tid >> 6, lane = tid & 63;
  const int rq = lane >> 4, cq = lane & 15;   // 4 rows x 16 colquads per wave
  __shared__ __align__(16) float ldsW8[256*8];
  __shared__ __align__(16) float ldsP[4*16*32];

  {
    const float4* g = (const float4*)(ws + OFF_W8 + ((size_t)b*MM + slice*256)*8);
    ((float4*)ldsW8)[tid] = g[tid];
    ((float4*)ldsW8)[tid+256] = g[tid+256];
  }
  __syncthreads();

  const float4* mem4 = (const float4*)(memory + (size_t)b*MM*CC) + (size_t)slice*256*16;
  float4 acc[8];
  #pragma unroll
  for (int j=0;j<8;++j){ acc[j].x=0;acc[j].y=0;acc[j].z=0;acc[j].w=0; }

  #pragma unroll 4
  for (int i = 0; i < 16; ++i) {
    int m = w*64 + i*4 + rq;
    float4 v = mem4[m*16 + cq];
    float4 wa = *(const float4*)&ldsW8[m*8];
    float4 wb = *(const float4*)&ldsW8[m*8+4];
    #define ACC(j, s) { acc[j].x += (s)*v.x; acc[j].y += (s)*v.y; acc[j].z += (s)*v.z; acc[j].w += (s)*v.w; }
    ACC(0, wa.x) ACC(1, wa.y) ACC(2, wa.z) ACC(3, wa.w)
    ACC(4, wb.x) ACC(5, wb.y) ACC(6, wb.z) ACC(7, wb.w)
    #undef ACC
  }
  #pragma unroll
  for (int j=0;j<8;++j){
    #pragma unroll
    for (int off=16; off<64; off<<=1) {
      acc[j].x += __shfl_xor(acc[j].x, off);
      acc[j].y += __shfl_xor(acc[j].y, off);
      acc[j].z += __shfl_xor(acc[j].z, off);
      acc[j].w += __shfl_xor(acc[j].w, off);
    }
  }
  if (rq == 0) {
    float4* p4 = (float4*)&ldsP[(w*16 + cq)*32];
    #pragma unroll
    for (int j=0;j<8;++j) p4[j] = acc[j];
  }
  __syncthreads();
  {
    int jj = tid >> 6;
    int c  = tid & 63;
    int cq2 = c >> 2, ci = c & 3;
    float s1 = 0.f, s2 = 0.f;
    #pragma unroll
    for (int g=0; g<4; ++g) {
      s1 += ldsP[(g*16 + cq2)*32 +  jj*4    + ci];
      s2 += ldsP[(g*16 + cq2)*32 + (jj+4)*4 + ci];
    }
    float* part = wso + OFF_PART + (((size_t)b*8 + slice)*8)*64;
    part[ jj   *64 + c] = s1;
    part[(jj+4)*64 + c] = s2;
  }
}

// ================= K5: combine slices, apply erase/write terms ============
__global__ __launch_bounds__(256) void k5_combine(
    const float* __restrict__ ws, float* __restrict__ out)
{
  const int b = blockIdx.x, tid = threadIdx.x;
  const int h = tid >> 6, c = tid & 63;
  const float* P = ws + OFF_P + (size_t)b*512;
  float S1 = 0.f, S2 = 0.f;
  #pragma unroll
  for (int s = 0; s < 8; ++s) {
    const float* part = ws + OFF_PART + (((size_t)b*8 + s)*8)*64;
    S1 += part[ h   *64 + c];
    S2 += part[(h+4)*64 + c];
  }
  float e  = P[320+c];
  float wv = P[384+c];
  float cr = ws[OFF_CR + (size_t)b*4 + h];
  out[((size_t)b<<8) + h*64 + c] = S1 - e*S2 + cr*wv;
}

extern "C" void kernel_launch(void* const* d_in, const int* in_sizes, int n_in,
                              void* d_out, int out_size, void* d_ws, size_t ws_size,
                              hipStream_t stream) {
  const float* xi      = (const float*)d_in[0];
  const float* W       = (const float*)d_in[1];
  const float* gamma   = (const float*)d_in[2];
  const float* beta    = (const float*)d_in[3];
  const float* memory  = (const float*)d_in[4];
  const float* read_w  = (const float*)d_in[5];
  const float* write_w = (const float*)d_in[6];
  const float* usage   = (const float*)d_in[7];
  float* ws  = (float*)d_ws;
  float* out = (float*)d_out;

  k1_interface<<<dim3(256), dim3(512), 0, stream>>>(xi, W, gamma, beta, read_w, write_w, usage, ws);
  k2_fused   <<<dim3(2304), dim3(256), 0, stream>>>(memory, ws);
  k3_weights <<<dim3(256), dim3(512), 0, stream>>>(ws);
  k4_reduce  <<<dim3(8,256), dim3(256), 0, stream>>>(memory, ws, ws);
  k5_combine <<<dim3(256), dim3(256), 0, stream>>>(ws, out);
}